// Round 1
// baseline (335.334 us; speedup 1.0000x reference)
//
#include <hip/hip_runtime.h>

#define H_KNOT 0.4f
#define CINC 64
#define COUT 64
#define GS 8      // GRID_SIZE + SPLINE_ORDER
#define HH 32
#define WW 32
#define BB 16
#define HP 34
#define WP 34
#define CC 8          // cin chunk
#define KC (CC*GS)    // 64

// Phase 1: B-spline bases of the zero-padded input.
// basesP layout: [b][y(34)][cin][g(8)][x(34)]
__global__ void bases_kernel(const float* __restrict__ x, float* __restrict__ basesP) {
    int idx = blockIdx.x * blockDim.x + threadIdx.x;
    const int total = BB * HP * CINC * WP;
    if (idx >= total) return;
    int xx = idx % WP;
    int t1 = idx / WP;
    int cin = t1 % CINC;
    int t2 = t1 / CINC;
    int y = t2 % HP;
    int b = t2 / HP;
    float v = 0.0f;
    if (y >= 1 && y <= HH && xx >= 1 && xx <= WW) {
        v = x[((b * CINC + cin) * HH + (y - 1)) * WW + (xx - 1)];
    }
    // knots t[j] = (j-3)*0.4 - 1,  j = 0..11
    float bs[11];
#pragma unroll
    for (int j = 0; j < 11; ++j) {
        float tj  = (float)(j - 3) * H_KNOT - 1.0f;
        float tj1 = (float)(j - 2) * H_KNOT - 1.0f;
        bs[j] = (v >= tj && v < tj1) ? 1.0f : 0.0f;
    }
#pragma unroll
    for (int k = 1; k <= 3; ++k) {
#pragma unroll
        for (int j = 0; j + k < 11; ++j) {
            float tj   = (float)(j - 3) * H_KNOT - 1.0f;
            float tj1  = (float)(j - 2) * H_KNOT - 1.0f;
            float tjk  = (float)(j + k - 3) * H_KNOT - 1.0f;
            float tjk1 = (float)(j + k - 2) * H_KNOT - 1.0f;
            float left  = (v - tj)   / (tjk  - tj)  * bs[j];
            float right = (tjk1 - v) / (tjk1 - tj1) * bs[j + 1];
            bs[j] = left + right;
        }
    }
    size_t base = (size_t)(((b * HP + y) * CINC + cin)) * GS * WP + xx;
#pragma unroll
    for (int g = 0; g < GS; ++g) {
        basesP[base + (size_t)g * WP] = bs[g];
    }
}

// Phase 1b: Wt[tap(9)][cin][g][oc] = sw[oc][cin][g][kh][kw] * sc[oc][cin]
__global__ void wt_kernel(const float* __restrict__ sw, const float* __restrict__ sc,
                          float* __restrict__ Wt) {
    int idx = blockIdx.x * blockDim.x + threadIdx.x;
    const int total = 9 * CINC * GS * COUT;
    if (idx >= total) return;
    int oc  = idx & 63;
    int g   = (idx >> 6) & 7;
    int cin = (idx >> 9) & 63;
    int tap = idx >> 15;
    int kh = tap / 3, kw = tap % 3;
    float w = sw[(((oc * CINC + cin) * GS + g) * 3 + kh) * 3 + kw] * sc[oc * CINC + cin];
    Wt[idx] = w;
}

// Phase 2: implicit-GEMM conv. One block per (b, h) output row.
// Thread t: pixel w = t>>3, output channels oc0..oc0+7 with oc0 = (t&7)*8.
__global__ __launch_bounds__(256) void conv_kernel(const float* __restrict__ basesP,
                                                   const float* __restrict__ Wt,
                                                   float* __restrict__ out) {
    __shared__ float A[3][KC][WP];     // 3*64*34 floats = 26112 B
    __shared__ float Bs[KC][COUT];     // 4096 floats = 16384 B
    int b = blockIdx.x >> 5;
    int h = blockIdx.x & 31;
    int t = threadIdx.x;
    int w = t >> 3;
    int oc0 = (t & 7) * 8;
    float acc[8];
#pragma unroll
    for (int j = 0; j < 8; ++j) acc[j] = 0.0f;

    for (int cc = 0; cc < CINC / CC; ++cc) {
        __syncthreads();   // previous iteration finished reading A
        // stage A: padded rows h..h+2, cin chunk, all g, all x
        for (int idx = t; idx < 3 * KC * WP; idx += 256) {
            int xx = idx % WP;
            int rest = idx / WP;
            int k = rest % KC;
            int kh = rest / KC;
            int cin = cc * CC + (k >> 3);
            int g = k & 7;
            A[kh][k][xx] = basesP[((size_t)((b * HP + (h + kh)) * CINC + cin) * GS + g) * WP + xx];
        }
        __syncthreads();
        for (int kh = 0; kh < 3; ++kh) {
            for (int kw = 0; kw < 3; ++kw) {
                __syncthreads();  // previous tap finished reading Bs
                const float4* src = (const float4*)(Wt +
                    ((size_t)(kh * 3 + kw) * CINC + cc * CC) * GS * COUT);
                for (int idx = t; idx < KC * COUT / 4; idx += 256) {
                    ((float4*)Bs)[idx] = src[idx];
                }
                __syncthreads();
#pragma unroll 8
                for (int k = 0; k < KC; ++k) {
                    float a = A[kh][k][w + kw];
                    float4 b0 = *(const float4*)&Bs[k][oc0];
                    float4 b1 = *(const float4*)&Bs[k][oc0 + 4];
                    acc[0] += a * b0.x;
                    acc[1] += a * b0.y;
                    acc[2] += a * b0.z;
                    acc[3] += a * b0.w;
                    acc[4] += a * b1.x;
                    acc[5] += a * b1.y;
                    acc[6] += a * b1.z;
                    acc[7] += a * b1.w;
                }
            }
        }
    }
    size_t obase = ((size_t)(b * COUT + oc0) * HH + h) * WW + w;
#pragma unroll
    for (int j = 0; j < 8; ++j) {
        out[obase + (size_t)j * HH * WW] = acc[j];
    }
}

extern "C" void kernel_launch(void* const* d_in, const int* in_sizes, int n_in,
                              void* d_out, int out_size, void* d_ws, size_t ws_size,
                              hipStream_t stream) {
    const float* x  = (const float*)d_in[0];
    const float* sw = (const float*)d_in[1];
    const float* sc = (const float*)d_in[2];
    float* out = (float*)d_out;
    float* ws = (float*)d_ws;
    float* basesP = ws;                                  // 16*34*64*8*34 = 9,469,952 floats
    float* Wt = ws + (size_t)BB * HP * CINC * GS * WP;   // + 294,912 floats (~39 MB total)

    {
        int total = BB * HP * CINC * WP;
        bases_kernel<<<(total + 255) / 256, 256, 0, stream>>>(x, basesP);
    }
    {
        int total = 9 * CINC * GS * COUT;
        wt_kernel<<<(total + 255) / 256, 256, 0, stream>>>(sw, sc, Wt);
    }
    conv_kernel<<<BB * HH, 256, 0, stream>>>(basesP, Wt, out);
}

// Round 2
// 149.941 us; speedup vs baseline: 2.2364x; 2.2364x over previous
//
#include <hip/hip_runtime.h>

#define CINC 64
#define COUT 64
#define GS 8
#define HH 32
#define WW 32
#define BB 16
#define HP 34
#define WP 34

typedef __attribute__((ext_vector_type(8))) short short8;
typedef __attribute__((ext_vector_type(4))) float floatx4;

__device__ __forceinline__ unsigned short f2bf(float f) {
    union { float f; unsigned int u; } c; c.f = f;
    unsigned int r = (c.u + 0x7FFFu + ((c.u >> 16) & 1u)) >> 16;
    return (unsigned short)r;
}

// basesG layout: [b][y(34)][x(34)][cin*8+g (512)] bf16
__global__ __launch_bounds__(256) void bases_kernel(const float* __restrict__ x,
                                                    short* __restrict__ basesG) {
    int idx = blockIdx.x * blockDim.x + threadIdx.x;
    const int total = BB * HP * WP * CINC;   // 1,183,744
    if (idx >= total) return;
    int cin = idx & 63;
    int xi = (idx >> 6) % WP;
    int rest = (idx >> 6) / WP;
    int y = rest % HP;
    int b = rest / HP;
    float v = 0.0f;
    if (y >= 1 && y <= HH && xi >= 1 && xi <= WW) {
        v = x[((b * CINC + cin) * HH + (y - 1)) * WW + (xi - 1)];
    }
    float bs[11];
#pragma unroll
    for (int j = 0; j < 11; ++j) {
        float tj  = (float)(j - 3) * 0.4f - 1.0f;
        float tj1 = (float)(j - 2) * 0.4f - 1.0f;
        bs[j] = (v >= tj && v < tj1) ? 1.0f : 0.0f;
    }
#pragma unroll
    for (int k = 1; k <= 3; ++k) {
#pragma unroll
        for (int j = 0; j + k < 11; ++j) {
            float tj   = (float)(j - 3) * 0.4f - 1.0f;
            float tj1  = (float)(j - 2) * 0.4f - 1.0f;
            float tjk  = (float)(j + k - 3) * 0.4f - 1.0f;
            float tjk1 = (float)(j + k - 2) * 0.4f - 1.0f;
            bs[j] = (v - tj) / (tjk - tj) * bs[j] + (tjk1 - v) / (tjk1 - tj1) * bs[j + 1];
        }
    }
    short out8[8];
#pragma unroll
    for (int g = 0; g < 8; ++g) out8[g] = (short)f2bf(bs[g]);
    size_t base = ((size_t)((b * HP + y) * WP + xi)) * 512 + (size_t)cin * 8;
    *(int4*)(basesG + base) = *(const int4*)out8;
}

// W2 layout: [tap(9)][oc(64)][cin*8+g (512)] bf16
__global__ __launch_bounds__(256) void wt_kernel(const float* __restrict__ sw,
                                                 const float* __restrict__ sc,
                                                 short* __restrict__ W2) {
    int idx = blockIdx.x * blockDim.x + threadIdx.x;
    const int total = 9 * COUT * 512;   // 294,912
    if (idx >= total) return;
    int k = idx & 511;
    int oc = (idx >> 9) & 63;
    int tap = idx >> 15;
    int cin = k >> 3;
    int g = k & 7;
    int kh = tap / 3, kw = tap % 3;
    float w = sw[(((oc * CINC + cin) * GS + g) * 3 + kh) * 3 + kw] * sc[oc * CINC + cin];
    W2[idx] = (short)f2bf(w);
}

__global__ __launch_bounds__(256) void zero_kernel(float4* __restrict__ out) {
    int idx = blockIdx.x * blockDim.x + threadIdx.x;
    out[idx] = make_float4(0.f, 0.f, 0.f, 0.f);
}

// Implicit-GEMM conv with MFMA. Grid: 256 blocks = 128 m-blocks x 2 cin halves.
// Block: 256 threads = 4 waves; M=128 pixels (4 output rows), N=64 oc.
// Wave (msub = wave>>1, nh = wave&1): 64m x 32n.
__global__ __launch_bounds__(256) void conv_kernel(const short* __restrict__ basesG,
                                                   const short* __restrict__ W2,
                                                   float* __restrict__ out) {
    __shared__ short Abuf[6 * 34 * 128];   // 52,224 B. [r(6)][x(34)][k(128)], k XOR-swizzled by x&7

    const int ch = blockIdx.x & 1;         // cin half
    const int mb = blockIdx.x >> 1;
    const int b = mb >> 3;
    const int h0 = (mb & 7) * 4;
    const int t = threadIdx.x;
    const int wave = t >> 6;
    const int lane = t & 63;
    const int l15 = lane & 15;
    const int q = lane >> 4;
    const int msub = wave >> 1;            // 0,1 -> rows h0+2*msub .. +1
    const int n0 = (wave & 1) * 32;

    floatx4 acc[4][2];
#pragma unroll
    for (int mt = 0; mt < 4; ++mt)
#pragma unroll
        for (int nt = 0; nt < 2; ++nt) acc[mt][nt] = (floatx4)0.f;

    for (int cc = 0; cc < 2; ++cc) {
        __syncthreads();
        // stage A: 6 rows x 34 x x 128 k (bf16) as 3264 16B-groups
        for (int u = t; u < 6 * 34 * 16; u += 256) {
            int kg = u & 15;
            int rx = u >> 4;              // 0..203
            int xi = rx % 34;
            int r = rx / 34;
            const int4 v = *(const int4*)(basesG +
                ((size_t)((b * HP + (h0 + r)) * WP + xi)) * 512 + ch * 256 + cc * 128 + kg * 8);
            *(int4*)(Abuf + (rx) * 128 + (kg ^ (xi & 7)) * 8) = v;
        }
        __syncthreads();

#pragma unroll
        for (int tap = 0; tap < 9; ++tap) {
            const int kh = tap / 3, kw = tap % 3;
            // load B fragments for this (tap, cc), held in regs
            short8 bfrag[2][4];
#pragma unroll
            for (int nt = 0; nt < 2; ++nt) {
#pragma unroll
                for (int s = 0; s < 4; ++s) {
                    int oc = n0 + nt * 16 + l15;
                    bfrag[nt][s] = *(const short8*)(W2 +
                        ((size_t)(tap * 64 + oc)) * 512 + ch * 256 + cc * 128 + s * 32 + q * 8);
                }
            }
#pragma unroll
            for (int mt = 0; mt < 4; ++mt) {
                const int rloc = msub * 2 + (mt >> 1);
                const int w = (mt & 1) * 16 + l15;
                const int xi = w + kw;
                const short* arow = Abuf + ((rloc + kh) * 34 + xi) * 128;
#pragma unroll
                for (int s = 0; s < 4; ++s) {
                    short8 aFrag = *(const short8*)(arow + ((s * 4 + q) ^ (xi & 7)) * 8);
                    acc[mt][0] = __builtin_amdgcn_mfma_f32_16x16x32_bf16(aFrag, bfrag[0][s], acc[mt][0], 0, 0, 0);
                    acc[mt][1] = __builtin_amdgcn_mfma_f32_16x16x32_bf16(aFrag, bfrag[1][s], acc[mt][1], 0, 0, 0);
                }
            }
        }
    }

    // epilogue: D[m = q*4+reg][n = l15] per 16x16 tile; 2-way cin-split -> atomicAdd
#pragma unroll
    for (int mt = 0; mt < 4; ++mt) {
        const int rloc = msub * 2 + (mt >> 1);
        const int wbase = (mt & 1) * 16 + q * 4;
#pragma unroll
        for (int nt = 0; nt < 2; ++nt) {
            const int oc = n0 + nt * 16 + l15;
            float* op = out + ((size_t)(b * COUT + oc) * HH + (h0 + rloc)) * WW + wbase;
#pragma unroll
            for (int reg = 0; reg < 4; ++reg) {
                atomicAdd(op + reg, acc[mt][nt][reg]);
            }
        }
    }
}

extern "C" void kernel_launch(void* const* d_in, const int* in_sizes, int n_in,
                              void* d_out, int out_size, void* d_ws, size_t ws_size,
                              hipStream_t stream) {
    const float* x  = (const float*)d_in[0];
    const float* sw = (const float*)d_in[1];
    const float* sc = (const float*)d_in[2];
    float* out = (float*)d_out;
    short* ws = (short*)d_ws;
    short* basesG = ws;                                    // 16*34*34*512 = 9,469,952 bf16
    short* W2 = ws + (size_t)BB * HP * WP * 512;           // + 294,912 bf16  (~19.5 MB)

    zero_kernel<<<(out_size / 4 + 255) / 256, 256, 0, stream>>>((float4*)out);
    {
        int total = BB * HP * WP * CINC;
        bases_kernel<<<(total + 255) / 256, 256, 0, stream>>>(x, basesG);
    }
    {
        int total = 9 * COUT * 512;
        wt_kernel<<<(total + 255) / 256, 256, 0, stream>>>(sw, sc, W2);
    }
    conv_kernel<<<256, 256, 0, stream>>>(basesG, W2, out);
}